// Round 6
// baseline (1016.894 us; speedup 1.0000x reference)
//
#include <hip/hip_runtime.h>
#include <hip/hip_bf16.h>
#include <math.h>

#define RR 374
#define FF 128
#define NBT 576
#define KSEL 299
#define PROBN (NBT * RR)   // 215424

__device__ __forceinline__ float gelu_f(float v) {
    return 0.5f * v * (1.f + erff(v * 0.70710678118654752f));
}

__device__ __forceinline__ void fma4(float4& d, float s, const float4 w) {
    d.x = fmaf(s, w.x, d.x);
    d.y = fmaf(s, w.y, d.y);
    d.z = fmaf(s, w.z, d.z);
    d.w = fmaf(s, w.w, d.w);
}

// ---------------------------------------------------------------------------
// Kernel 1 (all-f32, two half-width passes over GEMM1):
//   pass A: LN -> xn . w1[:,64:128] -> gelu -> glob partial sums (registers)
//   glob -> gvec = b2 + (glob/374) . w2[64:,:]
//   pass B: LN -> xn . w1[:,0:64] -> gelu -> f32 local tile -> per-row
//           GEMM2(+gvec) -> GeLU -> GEMM3 -> softmax -> score+gumbel -> s0
// Deterministic (no atomics), no precision-losing staging.
// ---------------------------------------------------------------------------
__global__ __launch_bounds__(256) void k_front(
    const float* __restrict__ x, const float* __restrict__ u,
    const float* __restrict__ ln_w, const float* __restrict__ ln_b,
    const float* __restrict__ w1, const float* __restrict__ b1,
    const float* __restrict__ w2, const float* __restrict__ b2,
    const float* __restrict__ w3, const float* __restrict__ b3,
    float* __restrict__ s0out)
{
    __shared__ __align__(16) float Whalf[128 * 64];   // 32 KB (one half of w1)
    __shared__ __align__(16) float xn[32 * 132];      // 16.9 KB LN tile
    __shared__ __align__(16) float ltile[32 * 68];    // 8.7 KB f32 local tile
    __shared__ __align__(16) float w2s[128 * 32];     // 16 KB
    __shared__ __align__(16) float part[16 * 64];     // 4 KB glob partials
    __shared__ __align__(16) float globv[64];
    __shared__ __align__(16) float gvec[32];

    const int bt   = blockIdx.x;
    const int tid  = threadIdx.x;
    const int lane = tid & 63;
    const int wv   = tid >> 6;
    const int cg   = tid & 15;   // 4-col group (GEMM1)
    const int rg   = tid >> 4;   // 2-row group (GEMM1)

    const float* xbt = x + (size_t)bt * RR * FF;

    // stage w2 (full) and w1 hi-half
    for (int i = tid; i < 128 * 32; i += 256) w2s[i] = w2[i];
    for (int i = tid; i < 128 * 64; i += 256)
        Whalf[i] = w1[(i >> 6) * 128 + 64 + (i & 63)];
    __syncthreads();

    // ================= PASS A: hi half -> glob =================
    float ups[4] = {0.f, 0.f, 0.f, 0.f};
    for (int tile = 0; tile < 12; ++tile) {
        const int rows0 = tile * 32;

        // LN tile (rows of zeros beyond RR so GEMM can run unguarded)
        for (int rl = wv; rl < 32; rl += 4) {
            const int r = rows0 + rl;
            float2 v = make_float2(0.f, 0.f);
            if (r < RR) v = *(const float2*)&xbt[r * FF + 2 * lane];
            float s = v.x + v.y;
            #pragma unroll
            for (int o = 32; o > 0; o >>= 1) s += __shfl_xor(s, o);
            const float m = s / 128.f;
            const float dx = v.x - m, dy = v.y - m;
            float sq = dx * dx + dy * dy;
            #pragma unroll
            for (int o = 32; o > 0; o >>= 1) sq += __shfl_xor(sq, o);
            const float var  = sq / 128.f;
            const float rstd = 1.f / sqrtf(var + 1e-5f);
            const float2 lw = *(const float2*)&ln_w[2 * lane];
            const float2 lb = *(const float2*)&ln_b[2 * lane];
            float2 o2;
            o2.x = dx * rstd * lw.x + lb.x;
            o2.y = dy * rstd * lw.y + lb.y;
            *(float2*)&xn[rl * 132 + 2 * lane] = o2;
        }
        __syncthreads();

        float4 a0 = {0, 0, 0, 0}, a1 = {0, 0, 0, 0};
        const int r0l = 2 * rg;
        const float* xr0 = &xn[r0l * 132];
        const float* xr1 = xr0 + 132;
        #pragma unroll 4
        for (int k = 0; k < 128; k += 4) {
            const float4 v0 = *(const float4*)(xr0 + k);
            const float4 v1 = *(const float4*)(xr1 + k);
            #pragma unroll
            for (int kk = 0; kk < 4; ++kk) {
                const float s0k = kk == 0 ? v0.x : (kk == 1 ? v0.y : (kk == 2 ? v0.z : v0.w));
                const float s1k = kk == 0 ? v1.x : (kk == 1 ? v1.y : (kk == 2 ? v1.z : v1.w));
                const float4 wvv = *(const float4*)&Whalf[(k + kk) * 64 + 4 * cg];
                fma4(a0, s0k, wvv);
                fma4(a1, s1k, wvv);
            }
        }
        // gelu + accumulate hi sums (valid rows only)
        if (rows0 + r0l < RR) {
            ups[0] += gelu_f(a0.x + b1[64 + 4 * cg + 0]);
            ups[1] += gelu_f(a0.y + b1[64 + 4 * cg + 1]);
            ups[2] += gelu_f(a0.z + b1[64 + 4 * cg + 2]);
            ups[3] += gelu_f(a0.w + b1[64 + 4 * cg + 3]);
        }
        if (rows0 + r0l + 1 < RR) {
            ups[0] += gelu_f(a1.x + b1[64 + 4 * cg + 0]);
            ups[1] += gelu_f(a1.y + b1[64 + 4 * cg + 1]);
            ups[2] += gelu_f(a1.z + b1[64 + 4 * cg + 2]);
            ups[3] += gelu_f(a1.w + b1[64 + 4 * cg + 3]);
        }
        __syncthreads();   // xn about to be overwritten
    }

    // deterministic glob reduction
    #pragma unroll
    for (int c = 0; c < 4; ++c) part[rg * 64 + 4 * cg + c] = ups[c];
    __syncthreads();
    if (tid < 64) {
        float s = 0.f;
        for (int g = 0; g < 16; ++g) s += part[g * 64 + tid];
        globv[tid] = s / 374.f;          // true division, matches jnp.mean
    }
    __syncthreads();
    if (tid < 32) {
        float a = b2[tid];
        for (int c = 0; c < 64; ++c)
            a = fmaf(globv[c], w2s[(64 + c) * 32 + tid], a);
        gvec[tid] = a;
    }
    __syncthreads();

    // ================= PASS B: lo half -> local -> score =================
    for (int i = tid; i < 128 * 64; i += 256)
        Whalf[i] = w1[(i >> 6) * 128 + (i & 63)];
    __syncthreads();

    for (int tile = 0; tile < 12; ++tile) {
        const int rows0 = tile * 32;

        for (int rl = wv; rl < 32; rl += 4) {
            const int r = rows0 + rl;
            float2 v = make_float2(0.f, 0.f);
            if (r < RR) v = *(const float2*)&xbt[r * FF + 2 * lane];
            float s = v.x + v.y;
            #pragma unroll
            for (int o = 32; o > 0; o >>= 1) s += __shfl_xor(s, o);
            const float m = s / 128.f;
            const float dx = v.x - m, dy = v.y - m;
            float sq = dx * dx + dy * dy;
            #pragma unroll
            for (int o = 32; o > 0; o >>= 1) sq += __shfl_xor(sq, o);
            const float var  = sq / 128.f;
            const float rstd = 1.f / sqrtf(var + 1e-5f);
            const float2 lw = *(const float2*)&ln_w[2 * lane];
            const float2 lb = *(const float2*)&ln_b[2 * lane];
            float2 o2;
            o2.x = dx * rstd * lw.x + lb.x;
            o2.y = dy * rstd * lw.y + lb.y;
            *(float2*)&xn[rl * 132 + 2 * lane] = o2;
        }
        __syncthreads();

        float4 a0 = {0, 0, 0, 0}, a1 = {0, 0, 0, 0};
        const int r0l = 2 * rg;
        const float* xr0 = &xn[r0l * 132];
        const float* xr1 = xr0 + 132;
        #pragma unroll 4
        for (int k = 0; k < 128; k += 4) {
            const float4 v0 = *(const float4*)(xr0 + k);
            const float4 v1 = *(const float4*)(xr1 + k);
            #pragma unroll
            for (int kk = 0; kk < 4; ++kk) {
                const float s0k = kk == 0 ? v0.x : (kk == 1 ? v0.y : (kk == 2 ? v0.z : v0.w));
                const float s1k = kk == 0 ? v1.x : (kk == 1 ? v1.y : (kk == 2 ? v1.z : v1.w));
                const float4 wvv = *(const float4*)&Whalf[(k + kk) * 64 + 4 * cg];
                fma4(a0, s0k, wvv);
                fma4(a1, s1k, wvv);
            }
        }
        // f32 local tile (no precision loss)
        ltile[(r0l + 0) * 68 + 4 * cg + 0] = gelu_f(a0.x + b1[4 * cg + 0]);
        ltile[(r0l + 0) * 68 + 4 * cg + 1] = gelu_f(a0.y + b1[4 * cg + 1]);
        ltile[(r0l + 0) * 68 + 4 * cg + 2] = gelu_f(a0.z + b1[4 * cg + 2]);
        ltile[(r0l + 0) * 68 + 4 * cg + 3] = gelu_f(a0.w + b1[4 * cg + 3]);
        ltile[(r0l + 1) * 68 + 4 * cg + 0] = gelu_f(a1.x + b1[4 * cg + 0]);
        ltile[(r0l + 1) * 68 + 4 * cg + 1] = gelu_f(a1.y + b1[4 * cg + 1]);
        ltile[(r0l + 1) * 68 + 4 * cg + 2] = gelu_f(a1.z + b1[4 * cg + 2]);
        ltile[(r0l + 1) * 68 + 4 * cg + 3] = gelu_f(a1.w + b1[4 * cg + 3]);
        __syncthreads();

        // per-row GEMM2 + GeLU + GEMM3 + softmax + gumbel
        {
            const int row = tid >> 3;        // 0..31
            const int jg  = tid & 7;         // 4 h2-cols each
            const int r   = rows0 + row;
            float4 h2 = *(const float4*)&gvec[4 * jg];
            const float* lrow = &ltile[row * 68];
            #pragma unroll 8
            for (int c = 0; c < 64; ++c) {
                const float lv = lrow[c];
                const float4 wvv = *(const float4*)&w2s[c * 32 + 4 * jg];
                fma4(h2, lv, wvv);
            }
            float pl0 = 0.f, pl1 = 0.f;
            #pragma unroll
            for (int jj = 0; jj < 4; ++jj) {
                const int j = 4 * jg + jj;
                const float hv = jj == 0 ? h2.x : (jj == 1 ? h2.y : (jj == 2 ? h2.z : h2.w));
                const float ge = gelu_f(hv);
                pl0 = fmaf(ge, w3[2 * j + 0], pl0);
                pl1 = fmaf(ge, w3[2 * j + 1], pl1);
            }
            pl0 += __shfl_xor(pl0, 1); pl0 += __shfl_xor(pl0, 2); pl0 += __shfl_xor(pl0, 4);
            pl1 += __shfl_xor(pl1, 1); pl1 += __shfl_xor(pl1, 2); pl1 += __shfl_xor(pl1, 4);
            if (jg == 0 && r < RR) {
                const float l0 = pl0 + b3[0];
                const float l1 = pl1 + b3[1];
                const float m3 = fmaxf(l0, l1);
                const float e0 = expf(l0 - m3);
                const float e1 = expf(l1 - m3);
                const float sc = e1 / (e0 + e1);          // softmax[...,1]
                const float uu = u[(size_t)bt * RR + r];
                const float gmb = -logf(-logf(uu));
                s0out[(size_t)bt * RR + r] = sc + gmb;
            }
        }
        __syncthreads();
    }
}

// ---------------------------------------------------------------------------
// Kernel 2: subset operator, FAITHFUL log-domain (max-subtract softmax,
// true divisions, log-space suppression) + top-K via bitonic sort.
// One wave per (b,t); 6 elements/lane in registers.
// ---------------------------------------------------------------------------
__global__ __launch_bounds__(64) void k_subset(
    const float* __restrict__ s0, float* __restrict__ out)
{
    __shared__ unsigned long long keys[512];

    const int bt   = blockIdx.x;
    const int lane = threadIdx.x;

    float s[6], kh[6];
    #pragma unroll
    for (int i = 0; i < 6; ++i) {
        const int j = i * 64 + lane;
        s[i]  = (j < RR) ? s0[(size_t)bt * RR + j] : -INFINITY;
        kh[i] = 0.f;
    }

    for (int it = 0; it < KSEL; ++it) {
        // softmax(s) with max-subtract, exactly like jax.nn.softmax
        float m = fmaxf(fmaxf(fmaxf(s[0], s[1]), fmaxf(s[2], s[3])), fmaxf(s[4], s[5]));
        #pragma unroll
        for (int o = 32; o > 0; o >>= 1) m = fmaxf(m, __shfl_xor(m, o));
        float e[6];
        #pragma unroll
        for (int i = 0; i < 6; ++i) e[i] = expf(s[i] - m);
        float z = ((e[0] + e[1]) + (e[2] + e[3])) + (e[4] + e[5]);
        #pragma unroll
        for (int o = 32; o > 0; o >>= 1) z += __shfl_xor(z, o);
        #pragma unroll
        for (int i = 0; i < 6; ++i) {
            const float oh = e[i] / z;                     // true division
            kh[i] += oh;
            s[i]  += logf(fmaxf(1.f - oh, 1.17549435e-38f)); // s += log(max(1-oh,EPS))
        }
    }

    // write prob
    #pragma unroll
    for (int i = 0; i < 6; ++i) {
        const int j = i * 64 + lane;
        if (j < RR) out[(size_t)bt * RR + j] = kh[i];
    }

    // ---- top-K: sort (value desc, index asc) via packed-u64 bitonic ----
    #pragma unroll
    for (int t = 0; t < 8; ++t) {
        const int idx = t * 64 + lane;
        unsigned long long key = 0ull;
        if (t < 6 && idx < RR) {
            key = (((unsigned long long)__float_as_uint(kh[t])) << 32)
                | (unsigned long long)(0xFFFFFFFFu - (unsigned)idx);
        }
        keys[idx] = key;
    }
    __syncthreads();

    for (int k = 2; k <= 512; k <<= 1) {
        for (int jj = k >> 1; jj > 0; jj >>= 1) {
            #pragma unroll
            for (int t = 0; t < 8; ++t) {
                const int i = t * 64 + lane;
                const int ixj = i ^ jj;
                if (ixj > i) {
                    const unsigned long long a = keys[i];
                    const unsigned long long b = keys[ixj];
                    const bool sw = ((i & k) == 0) ? (a < b) : (a > b);
                    if (sw) { keys[i] = b; keys[ixj] = a; }
                }
            }
            __syncthreads();
        }
    }

    for (int k2 = lane; k2 < KSEL; k2 += 64) {
        const unsigned idx = 0xFFFFFFFFu - (unsigned)(keys[k2] & 0xFFFFFFFFull);
        out[PROBN + (size_t)bt * KSEL + k2] = (float)idx;
    }
}

// ---------------------------------------------------------------------------
extern "C" void kernel_launch(void* const* d_in, const int* in_sizes, int n_in,
                              void* d_out, int out_size, void* d_ws, size_t ws_size,
                              hipStream_t stream)
{
    const float* x    = (const float*)d_in[0];
    const float* u    = (const float*)d_in[1];
    const float* ln_w = (const float*)d_in[2];
    const float* ln_b = (const float*)d_in[3];
    const float* w1   = (const float*)d_in[4];
    const float* b1   = (const float*)d_in[5];
    const float* w2   = (const float*)d_in[6];
    const float* b2   = (const float*)d_in[7];
    const float* w3   = (const float*)d_in[8];
    const float* b3   = (const float*)d_in[9];

    float* s0 = (float*)d_ws;           // 576*374 floats = 862 KB
    float* out = (float*)d_out;

    k_front<<<NBT, 256, 0, stream>>>(x, u, ln_w, ln_b, w1, b1, w2, b2, w3, b3, s0);
    k_subset<<<NBT, 64, 0, stream>>>(s0, out);
}

// Round 7
// 536.467 us; speedup vs baseline: 1.8955x; 1.8955x over previous
//
#include <hip/hip_runtime.h>
#include <hip/hip_bf16.h>
#include <math.h>

#define RR 374
#define FF 128
#define NBT 576
#define KSEL 299
#define PROBN (NBT * RR)   // 215424

__device__ __forceinline__ float gelu_f(float v) {
    return 0.5f * v * (1.f + erff(v * 0.70710678118654752f));
}

__device__ __forceinline__ void fma4(float4& d, float s, const float4 w) {
    d.x = fmaf(s, w.x, d.x);
    d.y = fmaf(s, w.y, d.y);
    d.z = fmaf(s, w.z, d.z);
    d.w = fmaf(s, w.w, d.w);
}

// ===========================================================================
// FAST PATH (needs ~59 MB workspace)
// ===========================================================================

// K1: (bt,tile) -> LN(32 rows) -> GEMM1 128 cols -> GeLU
//     lo 64 -> localo[bt][r][64] (f32); hi 64 -> per-tile partial sums.
__global__ __launch_bounds__(256) void k_gemm1(
    const float* __restrict__ x,
    const float* __restrict__ ln_w, const float* __restrict__ ln_b,
    const float* __restrict__ w1, const float* __restrict__ b1,
    float* __restrict__ localo, float* __restrict__ parto)
{
    __shared__ __align__(16) float xn[32 * 132];   // 16.9 KB
    __shared__ float part[16 * 64];                // 4 KB

    const int blk   = blockIdx.x;
    const int bt    = blk / 12;
    const int tile  = blk - bt * 12;
    const int rows0 = tile * 32;
    const int tid   = threadIdx.x;
    const int lane  = tid & 63;
    const int wv    = tid >> 6;
    const int cg    = tid & 15;
    const int rg    = tid >> 4;

    const float* xbt = x + (size_t)bt * RR * FF;

    // LayerNorm 32 rows (zeros beyond RR)
    for (int rl = wv; rl < 32; rl += 4) {
        const int r = rows0 + rl;
        float2 v = make_float2(0.f, 0.f);
        if (r < RR) v = *(const float2*)&xbt[r * FF + 2 * lane];
        float s = v.x + v.y;
        #pragma unroll
        for (int o = 32; o > 0; o >>= 1) s += __shfl_xor(s, o);
        const float m = s / 128.f;
        const float dx = v.x - m, dy = v.y - m;
        float sq = dx * dx + dy * dy;
        #pragma unroll
        for (int o = 32; o > 0; o >>= 1) sq += __shfl_xor(sq, o);
        const float var  = sq / 128.f;
        const float rstd = 1.f / sqrtf(var + 1e-5f);
        const float2 lw = *(const float2*)&ln_w[2 * lane];
        const float2 lb = *(const float2*)&ln_b[2 * lane];
        float2 o2;
        o2.x = dx * rstd * lw.x + lb.x;
        o2.y = dy * rstd * lw.y + lb.y;
        *(float2*)&xn[rl * 132 + 2 * lane] = o2;
    }
    __syncthreads();

    // GEMM: thread = 2 rows x (4 lo + 4 hi) cols, w1 straight from global/L2
    float4 aLo0{0,0,0,0}, aHi0{0,0,0,0}, aLo1{0,0,0,0}, aHi1{0,0,0,0};
    const int r0l = 2 * rg;
    const float* xr0 = &xn[r0l * 132];
    const float* xr1 = xr0 + 132;
    const float* wp  = w1 + 4 * cg;
    #pragma unroll 4
    for (int k = 0; k < 128; k += 4) {
        const float4 v0 = *(const float4*)(xr0 + k);
        const float4 v1 = *(const float4*)(xr1 + k);
        #pragma unroll
        for (int kk = 0; kk < 4; ++kk) {
            const float s0k = kk == 0 ? v0.x : (kk == 1 ? v0.y : (kk == 2 ? v0.z : v0.w));
            const float s1k = kk == 0 ? v1.x : (kk == 1 ? v1.y : (kk == 2 ? v1.z : v1.w));
            const float4 wl = *(const float4*)(wp + (k + kk) * 128);
            const float4 wh = *(const float4*)(wp + (k + kk) * 128 + 64);
            fma4(aLo0, s0k, wl);
            fma4(aHi0, s0k, wh);
            fma4(aLo1, s1k, wl);
            fma4(aHi1, s1k, wh);
        }
    }

    const int r0 = rows0 + r0l;
    const float4 bl = *(const float4*)&b1[4 * cg];
    const float4 bh = *(const float4*)&b1[64 + 4 * cg];

    if (r0 < RR) {
        float4 g;
        g.x = gelu_f(aLo0.x + bl.x);
        g.y = gelu_f(aLo0.y + bl.y);
        g.z = gelu_f(aLo0.z + bl.z);
        g.w = gelu_f(aLo0.w + bl.w);
        *(float4*)&localo[((size_t)bt * RR + r0) * 64 + 4 * cg] = g;
    }
    if (r0 + 1 < RR) {
        float4 g;
        g.x = gelu_f(aLo1.x + bl.x);
        g.y = gelu_f(aLo1.y + bl.y);
        g.z = gelu_f(aLo1.z + bl.z);
        g.w = gelu_f(aLo1.w + bl.w);
        *(float4*)&localo[((size_t)bt * RR + r0 + 1) * 64 + 4 * cg] = g;
    }
    float hs0 = 0.f, hs1 = 0.f, hs2 = 0.f, hs3 = 0.f;
    if (r0 < RR) {
        hs0 += gelu_f(aHi0.x + bh.x);
        hs1 += gelu_f(aHi0.y + bh.y);
        hs2 += gelu_f(aHi0.z + bh.z);
        hs3 += gelu_f(aHi0.w + bh.w);
    }
    if (r0 + 1 < RR) {
        hs0 += gelu_f(aHi1.x + bh.x);
        hs1 += gelu_f(aHi1.y + bh.y);
        hs2 += gelu_f(aHi1.z + bh.z);
        hs3 += gelu_f(aHi1.w + bh.w);
    }
    part[rg * 64 + 4 * cg + 0] = hs0;
    part[rg * 64 + 4 * cg + 1] = hs1;
    part[rg * 64 + 4 * cg + 2] = hs2;
    part[rg * 64 + 4 * cg + 3] = hs3;
    __syncthreads();
    if (tid < 64) {
        float s = 0.f;
        #pragma unroll
        for (int g = 0; g < 16; ++g) s += part[g * 64 + tid];
        parto[((size_t)bt * 12 + tile) * 64 + tid] = s;
    }
}

// K2: per bt: glob mean -> gvec = b2 + glob . w2[64:,:]
__global__ __launch_bounds__(64) void k_gvec(
    const float* __restrict__ parto, const float* __restrict__ w2,
    const float* __restrict__ b2, float* __restrict__ gvec_o)
{
    __shared__ float glob[64];
    const int bt  = blockIdx.x;
    const int tid = threadIdx.x;
    {
        float s = 0.f;
        #pragma unroll
        for (int t = 0; t < 12; ++t) s += parto[((size_t)bt * 12 + t) * 64 + tid];
        glob[tid] = s / 374.f;
    }
    __syncthreads();
    if (tid < 32) {
        float a = b2[tid];
        for (int c = 0; c < 64; ++c)
            a = fmaf(glob[c], w2[(64 + c) * 32 + tid], a);
        gvec_o[bt * 32 + tid] = a;
    }
}

// K3: (bt,tile): GEMM2(local . w2_lo + gvec) -> GeLU -> GEMM3 -> softmax
//     -> score + gumbel -> s0
__global__ __launch_bounds__(256) void k_score(
    const float* __restrict__ localo, const float* __restrict__ gvec_i,
    const float* __restrict__ w2, const float* __restrict__ w3,
    const float* __restrict__ b3, const float* __restrict__ u,
    float* __restrict__ s0out)
{
    __shared__ __align__(16) float w2s[64 * 32];   // lo half only, 8 KB
    __shared__ __align__(16) float lt[32 * 68];    // 8.7 KB
    __shared__ __align__(16) float gv[32];

    const int blk   = blockIdx.x;
    const int bt    = blk / 12;
    const int tile  = blk - bt * 12;
    const int rows0 = tile * 32;
    const int tid   = threadIdx.x;

    for (int i = tid; i < 64 * 32; i += 256) w2s[i] = w2[i];
    if (tid < 32) gv[tid] = gvec_i[bt * 32 + tid];
    for (int i = tid; i < 512; i += 256) {
        const int r = i >> 4, c4 = i & 15;
        float4 v = {0.f, 0.f, 0.f, 0.f};
        if (rows0 + r < RR)
            v = *(const float4*)&localo[((size_t)bt * RR + rows0 + r) * 64 + 4 * c4];
        *(float4*)&lt[r * 68 + 4 * c4] = v;
    }
    __syncthreads();

    const int row = tid >> 3;
    const int jg  = tid & 7;
    const int r   = rows0 + row;
    float4 h2 = *(const float4*)&gv[4 * jg];
    const float* lrow = &lt[row * 68];
    #pragma unroll 8
    for (int c = 0; c < 64; ++c)
        fma4(h2, lrow[c], *(const float4*)&w2s[c * 32 + 4 * jg]);

    float pl0 = 0.f, pl1 = 0.f;
    #pragma unroll
    for (int jj = 0; jj < 4; ++jj) {
        const int j = 4 * jg + jj;
        const float hv = jj == 0 ? h2.x : (jj == 1 ? h2.y : (jj == 2 ? h2.z : h2.w));
        const float ge = gelu_f(hv);
        pl0 = fmaf(ge, w3[2 * j + 0], pl0);
        pl1 = fmaf(ge, w3[2 * j + 1], pl1);
    }
    pl0 += __shfl_xor(pl0, 1); pl0 += __shfl_xor(pl0, 2); pl0 += __shfl_xor(pl0, 4);
    pl1 += __shfl_xor(pl1, 1); pl1 += __shfl_xor(pl1, 2); pl1 += __shfl_xor(pl1, 4);
    if (jg == 0 && r < RR) {
        const float l0 = pl0 + b3[0];
        const float l1 = pl1 + b3[1];
        const float m3 = fmaxf(l0, l1);
        const float e0 = expf(l0 - m3);
        const float e1 = expf(l1 - m3);
        const float sc = e1 / (e0 + e1);
        const float uu = u[(size_t)bt * RR + r];
        const float gmb = -logf(-logf(uu));
        s0out[(size_t)bt * RR + r] = sc + gmb;
    }
}

// ===========================================================================
// FALLBACK PATH: proven monolithic k_front (Round 6, passing)
// ===========================================================================
__global__ __launch_bounds__(256) void k_front(
    const float* __restrict__ x, const float* __restrict__ u,
    const float* __restrict__ ln_w, const float* __restrict__ ln_b,
    const float* __restrict__ w1, const float* __restrict__ b1,
    const float* __restrict__ w2, const float* __restrict__ b2,
    const float* __restrict__ w3, const float* __restrict__ b3,
    float* __restrict__ s0out)
{
    __shared__ __align__(16) float Whalf[128 * 64];
    __shared__ __align__(16) float xn[32 * 132];
    __shared__ __align__(16) float ltile[32 * 68];
    __shared__ __align__(16) float w2s[128 * 32];
    __shared__ __align__(16) float part[16 * 64];
    __shared__ __align__(16) float globv[64];
    __shared__ __align__(16) float gvec[32];

    const int bt   = blockIdx.x;
    const int tid  = threadIdx.x;
    const int lane = tid & 63;
    const int wv   = tid >> 6;
    const int cg   = tid & 15;
    const int rg   = tid >> 4;

    const float* xbt = x + (size_t)bt * RR * FF;

    for (int i = tid; i < 128 * 32; i += 256) w2s[i] = w2[i];
    for (int i = tid; i < 128 * 64; i += 256)
        Whalf[i] = w1[(i >> 6) * 128 + 64 + (i & 63)];
    __syncthreads();

    float ups[4] = {0.f, 0.f, 0.f, 0.f};
    for (int tile = 0; tile < 12; ++tile) {
        const int rows0 = tile * 32;
        for (int rl = wv; rl < 32; rl += 4) {
            const int r = rows0 + rl;
            float2 v = make_float2(0.f, 0.f);
            if (r < RR) v = *(const float2*)&xbt[r * FF + 2 * lane];
            float s = v.x + v.y;
            #pragma unroll
            for (int o = 32; o > 0; o >>= 1) s += __shfl_xor(s, o);
            const float m = s / 128.f;
            const float dx = v.x - m, dy = v.y - m;
            float sq = dx * dx + dy * dy;
            #pragma unroll
            for (int o = 32; o > 0; o >>= 1) sq += __shfl_xor(sq, o);
            const float var  = sq / 128.f;
            const float rstd = 1.f / sqrtf(var + 1e-5f);
            const float2 lw = *(const float2*)&ln_w[2 * lane];
            const float2 lb = *(const float2*)&ln_b[2 * lane];
            float2 o2;
            o2.x = dx * rstd * lw.x + lb.x;
            o2.y = dy * rstd * lw.y + lb.y;
            *(float2*)&xn[rl * 132 + 2 * lane] = o2;
        }
        __syncthreads();

        float4 a0 = {0, 0, 0, 0}, a1 = {0, 0, 0, 0};
        const int r0l = 2 * rg;
        const float* xr0 = &xn[r0l * 132];
        const float* xr1 = xr0 + 132;
        #pragma unroll 4
        for (int k = 0; k < 128; k += 4) {
            const float4 v0 = *(const float4*)(xr0 + k);
            const float4 v1 = *(const float4*)(xr1 + k);
            #pragma unroll
            for (int kk = 0; kk < 4; ++kk) {
                const float s0k = kk == 0 ? v0.x : (kk == 1 ? v0.y : (kk == 2 ? v0.z : v0.w));
                const float s1k = kk == 0 ? v1.x : (kk == 1 ? v1.y : (kk == 2 ? v1.z : v1.w));
                const float4 wvv = *(const float4*)&Whalf[(k + kk) * 64 + 4 * cg];
                fma4(a0, s0k, wvv);
                fma4(a1, s1k, wvv);
            }
        }
        if (rows0 + r0l < RR) {
            ups[0] += gelu_f(a0.x + b1[64 + 4 * cg + 0]);
            ups[1] += gelu_f(a0.y + b1[64 + 4 * cg + 1]);
            ups[2] += gelu_f(a0.z + b1[64 + 4 * cg + 2]);
            ups[3] += gelu_f(a0.w + b1[64 + 4 * cg + 3]);
        }
        if (rows0 + r0l + 1 < RR) {
            ups[0] += gelu_f(a1.x + b1[64 + 4 * cg + 0]);
            ups[1] += gelu_f(a1.y + b1[64 + 4 * cg + 1]);
            ups[2] += gelu_f(a1.z + b1[64 + 4 * cg + 2]);
            ups[3] += gelu_f(a1.w + b1[64 + 4 * cg + 3]);
        }
        __syncthreads();
    }

    #pragma unroll
    for (int c = 0; c < 4; ++c) part[rg * 64 + 4 * cg + c] = ups[c];
    __syncthreads();
    if (tid < 64) {
        float s = 0.f;
        for (int g = 0; g < 16; ++g) s += part[g * 64 + tid];
        globv[tid] = s / 374.f;
    }
    __syncthreads();
    if (tid < 32) {
        float a = b2[tid];
        for (int c = 0; c < 64; ++c)
            a = fmaf(globv[c], w2s[(64 + c) * 32 + tid], a);
        gvec[tid] = a;
    }
    __syncthreads();

    for (int i = tid; i < 128 * 64; i += 256)
        Whalf[i] = w1[(i >> 6) * 128 + (i & 63)];
    __syncthreads();

    for (int tile = 0; tile < 12; ++tile) {
        const int rows0 = tile * 32;
        for (int rl = wv; rl < 32; rl += 4) {
            const int r = rows0 + rl;
            float2 v = make_float2(0.f, 0.f);
            if (r < RR) v = *(const float2*)&xbt[r * FF + 2 * lane];
            float s = v.x + v.y;
            #pragma unroll
            for (int o = 32; o > 0; o >>= 1) s += __shfl_xor(s, o);
            const float m = s / 128.f;
            const float dx = v.x - m, dy = v.y - m;
            float sq = dx * dx + dy * dy;
            #pragma unroll
            for (int o = 32; o > 0; o >>= 1) sq += __shfl_xor(sq, o);
            const float var  = sq / 128.f;
            const float rstd = 1.f / sqrtf(var + 1e-5f);
            const float2 lw = *(const float2*)&ln_w[2 * lane];
            const float2 lb = *(const float2*)&ln_b[2 * lane];
            float2 o2;
            o2.x = dx * rstd * lw.x + lb.x;
            o2.y = dy * rstd * lw.y + lb.y;
            *(float2*)&xn[rl * 132 + 2 * lane] = o2;
        }
        __syncthreads();

        float4 a0 = {0, 0, 0, 0}, a1 = {0, 0, 0, 0};
        const int r0l = 2 * rg;
        const float* xr0 = &xn[r0l * 132];
        const float* xr1 = xr0 + 132;
        #pragma unroll 4
        for (int k = 0; k < 128; k += 4) {
            const float4 v0 = *(const float4*)(xr0 + k);
            const float4 v1 = *(const float4*)(xr1 + k);
            #pragma unroll
            for (int kk = 0; kk < 4; ++kk) {
                const float s0k = kk == 0 ? v0.x : (kk == 1 ? v0.y : (kk == 2 ? v0.z : v0.w));
                const float s1k = kk == 0 ? v1.x : (kk == 1 ? v1.y : (kk == 2 ? v1.z : v1.w));
                const float4 wvv = *(const float4*)&Whalf[(k + kk) * 64 + 4 * cg];
                fma4(a0, s0k, wvv);
                fma4(a1, s1k, wvv);
            }
        }
        ltile[(r0l + 0) * 68 + 4 * cg + 0] = gelu_f(a0.x + b1[4 * cg + 0]);
        ltile[(r0l + 0) * 68 + 4 * cg + 1] = gelu_f(a0.y + b1[4 * cg + 1]);
        ltile[(r0l + 0) * 68 + 4 * cg + 2] = gelu_f(a0.z + b1[4 * cg + 2]);
        ltile[(r0l + 0) * 68 + 4 * cg + 3] = gelu_f(a0.w + b1[4 * cg + 3]);
        ltile[(r0l + 1) * 68 + 4 * cg + 0] = gelu_f(a1.x + b1[4 * cg + 0]);
        ltile[(r0l + 1) * 68 + 4 * cg + 1] = gelu_f(a1.y + b1[4 * cg + 1]);
        ltile[(r0l + 1) * 68 + 4 * cg + 2] = gelu_f(a1.z + b1[4 * cg + 2]);
        ltile[(r0l + 1) * 68 + 4 * cg + 3] = gelu_f(a1.w + b1[4 * cg + 3]);
        __syncthreads();

        {
            const int row = tid >> 3;
            const int jg  = tid & 7;
            const int r   = rows0 + row;
            float4 h2 = *(const float4*)&gvec[4 * jg];
            const float* lrow = &ltile[row * 68];
            #pragma unroll 8
            for (int c = 0; c < 64; ++c) {
                const float lv = lrow[c];
                const float4 wvv = *(const float4*)&w2s[c * 32 + 4 * jg];
                fma4(h2, lv, wvv);
            }
            float pl0 = 0.f, pl1 = 0.f;
            #pragma unroll
            for (int jj = 0; jj < 4; ++jj) {
                const int j = 4 * jg + jj;
                const float hv = jj == 0 ? h2.x : (jj == 1 ? h2.y : (jj == 2 ? h2.z : h2.w));
                const float ge = gelu_f(hv);
                pl0 = fmaf(ge, w3[2 * j + 0], pl0);
                pl1 = fmaf(ge, w3[2 * j + 1], pl1);
            }
            pl0 += __shfl_xor(pl0, 1); pl0 += __shfl_xor(pl0, 2); pl0 += __shfl_xor(pl0, 4);
            pl1 += __shfl_xor(pl1, 1); pl1 += __shfl_xor(pl1, 2); pl1 += __shfl_xor(pl1, 4);
            if (jg == 0 && r < RR) {
                const float l0 = pl0 + b3[0];
                const float l1 = pl1 + b3[1];
                const float m3 = fmaxf(l0, l1);
                const float e0 = expf(l0 - m3);
                const float e1 = expf(l1 - m3);
                const float sc = e1 / (e0 + e1);
                const float uu = u[(size_t)bt * RR + r];
                const float gmb = -logf(-logf(uu));
                s0out[(size_t)bt * RR + r] = sc + gmb;
            }
        }
        __syncthreads();
    }
}

// ===========================================================================
// Kernel: subset operator (exp-domain, no transcendentals in the loop)
//         + top-K via bitonic sort (value desc, index asc)
// ===========================================================================
__global__ __launch_bounds__(64) void k_subset(
    const float* __restrict__ s0, float* __restrict__ out)
{
    __shared__ unsigned long long keys[512];

    const int bt   = blockIdx.x;
    const int lane = threadIdx.x;

    float S[6], kh[6];
    #pragma unroll
    for (int i = 0; i < 6; ++i) {
        const int j = i * 64 + lane;
        S[i]  = (j < RR) ? expf(s0[(size_t)bt * RR + j]) : 0.f;  // s <= ~14.9
        kh[i] = 0.f;
    }

    for (int it = 0; it < KSEL; ++it) {
        float z = ((S[0] + S[1]) + (S[2] + S[3])) + (S[4] + S[5]);
        #pragma unroll
        for (int o = 32; o > 0; o >>= 1) z += __shfl_xor(z, o);
        const float inv = 1.f / z;
        #pragma unroll
        for (int i = 0; i < 6; ++i) {
            const float oh = S[i] * inv;                    // softmax(s)
            kh[i] += oh;
            S[i] *= fmaxf(1.f - oh, 1.17549435e-38f);       // s += log(max(1-oh,EPS))
        }
    }

    #pragma unroll
    for (int i = 0; i < 6; ++i) {
        const int j = i * 64 + lane;
        if (j < RR) out[(size_t)bt * RR + j] = kh[i];
    }

    #pragma unroll
    for (int t = 0; t < 8; ++t) {
        const int idx = t * 64 + lane;
        unsigned long long key = 0ull;
        if (t < 6 && idx < RR) {
            key = (((unsigned long long)__float_as_uint(kh[t])) << 32)
                | (unsigned long long)(0xFFFFFFFFu - (unsigned)idx);
        }
        keys[idx] = key;
    }
    __syncthreads();

    for (int k = 2; k <= 512; k <<= 1) {
        for (int jj = k >> 1; jj > 0; jj >>= 1) {
            #pragma unroll
            for (int t = 0; t < 8; ++t) {
                const int i = t * 64 + lane;
                const int ixj = i ^ jj;
                if (ixj > i) {
                    const unsigned long long a = keys[i];
                    const unsigned long long b = keys[ixj];
                    const bool sw = ((i & k) == 0) ? (a < b) : (a > b);
                    if (sw) { keys[i] = b; keys[ixj] = a; }
                }
            }
            __syncthreads();
        }
    }

    for (int k2 = lane; k2 < KSEL; k2 += 64) {
        const unsigned idx = 0xFFFFFFFFu - (unsigned)(keys[k2] & 0xFFFFFFFFull);
        out[PROBN + (size_t)bt * KSEL + k2] = (float)idx;
    }
}

// ===========================================================================
extern "C" void kernel_launch(void* const* d_in, const int* in_sizes, int n_in,
                              void* d_out, int out_size, void* d_ws, size_t ws_size,
                              hipStream_t stream)
{
    const float* x    = (const float*)d_in[0];
    const float* u    = (const float*)d_in[1];
    const float* ln_w = (const float*)d_in[2];
    const float* ln_b = (const float*)d_in[3];
    const float* w1   = (const float*)d_in[4];
    const float* b1   = (const float*)d_in[5];
    const float* w2   = (const float*)d_in[6];
    const float* b2   = (const float*)d_in[7];
    const float* w3   = (const float*)d_in[8];
    const float* b3   = (const float*)d_in[9];

    float* s0  = (float*)d_ws;
    float* out = (float*)d_out;

    const size_t n_local = (size_t)NBT * RR * 64;
    const size_t n_part  = (size_t)NBT * 12 * 64;
    const size_t n_gvec  = (size_t)NBT * 32;
    const size_t need    = ((size_t)PROBN + n_local + n_part + n_gvec) * sizeof(float);

    if (ws_size >= need) {
        float* localo = s0 + PROBN;
        float* parto  = localo + n_local;
        float* gvecb  = parto + n_part;
        k_gemm1<<<NBT * 12, 256, 0, stream>>>(x, ln_w, ln_b, w1, b1, localo, parto);
        k_gvec <<<NBT,      64,  0, stream>>>(parto, w2, b2, gvecb);
        k_score<<<NBT * 12, 256, 0, stream>>>(localo, gvecb, w2, w3, b3, u, s0);
    } else {
        k_front<<<NBT, 256, 0, stream>>>(x, u, ln_w, ln_b, w1, b1, w2, b2, w3, b3, s0);
    }
    k_subset<<<NBT, 64, 0, stream>>>(s0, out);
}

// Round 9
// 424.106 us; speedup vs baseline: 2.3977x; 1.2649x over previous
//
#include <hip/hip_runtime.h>
#include <hip/hip_bf16.h>
#include <math.h>

#define RR 374
#define FF 128
#define NBT 576
#define KSEL 299
#define PROBN (NBT * RR)   // 215424
#define NT 6               // 64-row tiles per (b,t)

__device__ __forceinline__ float gelu_f(float v) {
    return 0.5f * v * (1.f + erff(v * 0.70710678118654752f));
}

__device__ __forceinline__ void fma4(float4& d, float s, const float4 w) {
    d.x = fmaf(s, w.x, d.x);
    d.y = fmaf(s, w.y, d.y);
    d.z = fmaf(s, w.z, d.z);
    d.w = fmaf(s, w.w, d.w);
}

// 64-lane sum via DPP (row_shr scan + row bcasts), result uniform via readlane.
__device__ __forceinline__ float wsum64(float v) {
    v += __int_as_float(__builtin_amdgcn_update_dpp(0, __float_as_int(v), 0x111, 0xf, 0xf, true));
    v += __int_as_float(__builtin_amdgcn_update_dpp(0, __float_as_int(v), 0x112, 0xf, 0xf, true));
    v += __int_as_float(__builtin_amdgcn_update_dpp(0, __float_as_int(v), 0x114, 0xf, 0xf, true));
    v += __int_as_float(__builtin_amdgcn_update_dpp(0, __float_as_int(v), 0x118, 0xf, 0xf, true));
    v += __int_as_float(__builtin_amdgcn_update_dpp(0, __float_as_int(v), 0x142, 0xa, 0xf, true)); // bcast15 -> rows 1,3
    v += __int_as_float(__builtin_amdgcn_update_dpp(0, __float_as_int(v), 0x143, 0xc, 0xf, true)); // bcast31 -> rows 2,3
    return __int_as_float(__builtin_amdgcn_readlane(__float_as_int(v), 63));
}

// ===========================================================================
// K1: (bt, tile64) -> LN(64 rows) -> GEMM1 (thread = 4 rows x (4 lo + 4 hi))
//     lo -> localo f32; hi -> gelu-summed per-tile partials.
// ===========================================================================
__global__ __launch_bounds__(256, 4) void k_gemm1(
    const float* __restrict__ x,
    const float* __restrict__ ln_w, const float* __restrict__ ln_b,
    const float* __restrict__ w1, const float* __restrict__ b1,
    float* __restrict__ localo, float* __restrict__ parto)
{
    __shared__ __align__(16) float xn[64 * 132];   // 33.8 KB
    __shared__ float part[16 * 64];                // 4 KB

    const int blk   = blockIdx.x;
    const int bt    = blk / NT;
    const int tile  = blk - bt * NT;
    const int rows0 = tile * 64;
    const int tid   = threadIdx.x;
    const int lane  = tid & 63;
    const int wv    = tid >> 6;
    const int cg    = tid & 15;
    const int rg    = tid >> 4;

    const float* xbt = x + (size_t)bt * RR * FF;

    // ---- LayerNorm 64 rows (zeros beyond RR), DPP reductions ----
    for (int rl = wv; rl < 64; rl += 4) {
        const int r = rows0 + rl;
        float2 v = make_float2(0.f, 0.f);
        if (r < RR) v = *(const float2*)&xbt[r * FF + 2 * lane];
        const float m = wsum64(v.x + v.y) * (1.f / 128.f);
        const float dx = v.x - m, dy = v.y - m;
        const float var = wsum64(dx * dx + dy * dy) * (1.f / 128.f);
        const float rstd = 1.f / sqrtf(var + 1e-5f);
        const float2 lw = *(const float2*)&ln_w[2 * lane];
        const float2 lb = *(const float2*)&ln_b[2 * lane];
        float2 o2;
        o2.x = dx * rstd * lw.x + lb.x;
        o2.y = dy * rstd * lw.y + lb.y;
        *(float2*)&xn[rl * 132 + 2 * lane] = o2;
    }
    __syncthreads();

    // ---- GEMM: 4 rows x 8 cols per thread, w1 streamed from L1/L2 ----
    float4 acL[4] = {{0,0,0,0},{0,0,0,0},{0,0,0,0},{0,0,0,0}};
    float4 acH[4] = {{0,0,0,0},{0,0,0,0},{0,0,0,0},{0,0,0,0}};
    const int r0l = 4 * rg;
    const float* wp = w1 + 4 * cg;

    for (int k = 0; k < 128; k += 4) {
        float4 xv0 = *(const float4*)&xn[(r0l + 0) * 132 + k];
        float4 xv1 = *(const float4*)&xn[(r0l + 1) * 132 + k];
        float4 xv2 = *(const float4*)&xn[(r0l + 2) * 132 + k];
        float4 xv3 = *(const float4*)&xn[(r0l + 3) * 132 + k];
        #pragma unroll
        for (int kk = 0; kk < 4; ++kk) {
            const float4 wl = *(const float4*)(wp + (k + kk) * 128);
            const float4 wh = *(const float4*)(wp + (k + kk) * 128 + 64);
            const float s0 = kk == 0 ? xv0.x : (kk == 1 ? xv0.y : (kk == 2 ? xv0.z : xv0.w));
            const float s1 = kk == 0 ? xv1.x : (kk == 1 ? xv1.y : (kk == 2 ? xv1.z : xv1.w));
            const float s2 = kk == 0 ? xv2.x : (kk == 1 ? xv2.y : (kk == 2 ? xv2.z : xv2.w));
            const float s3 = kk == 0 ? xv3.x : (kk == 1 ? xv3.y : (kk == 2 ? xv3.z : xv3.w));
            fma4(acL[0], s0, wl); fma4(acH[0], s0, wh);
            fma4(acL[1], s1, wl); fma4(acH[1], s1, wh);
            fma4(acL[2], s2, wl); fma4(acH[2], s2, wh);
            fma4(acL[3], s3, wl); fma4(acH[3], s3, wh);
        }
    }

    // ---- epilogue ----
    const float4 bl = *(const float4*)&b1[4 * cg];
    const float4 bh = *(const float4*)&b1[64 + 4 * cg];
    float hs0 = 0.f, hs1 = 0.f, hs2 = 0.f, hs3 = 0.f;
    #pragma unroll
    for (int i = 0; i < 4; ++i) {
        const int r = rows0 + r0l + i;
        if (r < RR) {
            float4 g;
            g.x = gelu_f(acL[i].x + bl.x);
            g.y = gelu_f(acL[i].y + bl.y);
            g.z = gelu_f(acL[i].z + bl.z);
            g.w = gelu_f(acL[i].w + bl.w);
            *(float4*)&localo[((size_t)bt * RR + r) * 64 + 4 * cg] = g;
            hs0 += gelu_f(acH[i].x + bh.x);
            hs1 += gelu_f(acH[i].y + bh.y);
            hs2 += gelu_f(acH[i].z + bh.z);
            hs3 += gelu_f(acH[i].w + bh.w);
        }
    }
    part[rg * 64 + 4 * cg + 0] = hs0;
    part[rg * 64 + 4 * cg + 1] = hs1;
    part[rg * 64 + 4 * cg + 2] = hs2;
    part[rg * 64 + 4 * cg + 3] = hs3;
    __syncthreads();
    if (tid < 64) {
        float s = 0.f;
        #pragma unroll
        for (int g = 0; g < 16; ++g) s += part[g * 64 + tid];
        parto[((size_t)bt * NT + tile) * 64 + tid] = s;
    }
}

// ===========================================================================
// K2: per bt: glob mean -> gvec = b2 + glob . w2[64:,:]
// ===========================================================================
__global__ __launch_bounds__(64) void k_gvec(
    const float* __restrict__ parto, const float* __restrict__ w2,
    const float* __restrict__ b2, float* __restrict__ gvec_o)
{
    __shared__ float glob[64];
    const int bt  = blockIdx.x;
    const int tid = threadIdx.x;
    {
        float s = 0.f;
        #pragma unroll
        for (int t = 0; t < NT; ++t) s += parto[((size_t)bt * NT + t) * 64 + tid];
        glob[tid] = s / 374.f;
    }
    __syncthreads();
    if (tid < 32) {
        float a = b2[tid];
        for (int c = 0; c < 64; ++c)
            a = fmaf(glob[c], w2[(64 + c) * 32 + tid], a);
        gvec_o[bt * 32 + tid] = a;
    }
}

// ===========================================================================
// K3: (bt, tile32): GEMM2 -> GeLU -> GEMM3 -> softmax -> score+gumbel -> s0
// ===========================================================================
__global__ __launch_bounds__(256, 4) void k_score(
    const float* __restrict__ localo, const float* __restrict__ gvec_i,
    const float* __restrict__ w2, const float* __restrict__ w3,
    const float* __restrict__ b3, const float* __restrict__ u,
    float* __restrict__ s0out)
{
    __shared__ __align__(16) float w2s[64 * 32];   // 8 KB (lo half)
    __shared__ __align__(16) float lt[32 * 68];    // 8.7 KB
    __shared__ __align__(16) float gv[32];

    const int blk   = blockIdx.x;
    const int bt    = blk / 12;
    const int tile  = blk - bt * 12;
    const int rows0 = tile * 32;
    const int tid   = threadIdx.x;

    for (int i = tid; i < 64 * 32; i += 256) w2s[i] = w2[i];
    if (tid < 32) gv[tid] = gvec_i[bt * 32 + tid];
    for (int i = tid; i < 512; i += 256) {
        const int r = i >> 4, c4 = i & 15;
        float4 v = {0.f, 0.f, 0.f, 0.f};
        if (rows0 + r < RR)
            v = *(const float4*)&localo[((size_t)bt * RR + rows0 + r) * 64 + 4 * c4];
        *(float4*)&lt[r * 68 + 4 * c4] = v;
    }
    __syncthreads();

    const int row = tid >> 3;
    const int jg  = tid & 7;
    const int r   = rows0 + row;
    float4 h2 = *(const float4*)&gv[4 * jg];
    const float* lrow = &lt[row * 68];
    #pragma unroll 8
    for (int c = 0; c < 64; ++c)
        fma4(h2, lrow[c], *(const float4*)&w2s[c * 32 + 4 * jg]);

    float pl0 = 0.f, pl1 = 0.f;
    #pragma unroll
    for (int jj = 0; jj < 4; ++jj) {
        const int j = 4 * jg + jj;
        const float hv = jj == 0 ? h2.x : (jj == 1 ? h2.y : (jj == 2 ? h2.z : h2.w));
        const float ge = gelu_f(hv);
        pl0 = fmaf(ge, w3[2 * j + 0], pl0);
        pl1 = fmaf(ge, w3[2 * j + 1], pl1);
    }
    pl0 += __shfl_xor(pl0, 1); pl0 += __shfl_xor(pl0, 2); pl0 += __shfl_xor(pl0, 4);
    pl1 += __shfl_xor(pl1, 1); pl1 += __shfl_xor(pl1, 2); pl1 += __shfl_xor(pl1, 4);
    if (jg == 0 && r < RR) {
        const float l0 = pl0 + b3[0];
        const float l1 = pl1 + b3[1];
        const float m3 = fmaxf(l0, l1);
        const float e0 = expf(l0 - m3);
        const float e1 = expf(l1 - m3);
        const float sc = e1 / (e0 + e1);
        const float uu = u[(size_t)bt * RR + r];
        const float gmb = -logf(-logf(uu));
        s0out[(size_t)bt * RR + r] = sc + gmb;
    }
}

// ===========================================================================
// FALLBACK: monolithic front (Round-6 proven), used only if ws too small
// ===========================================================================
__global__ __launch_bounds__(256) void k_front(
    const float* __restrict__ x, const float* __restrict__ u,
    const float* __restrict__ ln_w, const float* __restrict__ ln_b,
    const float* __restrict__ w1, const float* __restrict__ b1,
    const float* __restrict__ w2, const float* __restrict__ b2,
    const float* __restrict__ w3, const float* __restrict__ b3,
    float* __restrict__ s0out)
{
    __shared__ __align__(16) float Whalf[128 * 64];
    __shared__ __align__(16) float xn[32 * 132];
    __shared__ __align__(16) float ltile[32 * 68];
    __shared__ __align__(16) float w2s[128 * 32];
    __shared__ __align__(16) float part[16 * 64];
    __shared__ __align__(16) float globv[64];
    __shared__ __align__(16) float gvec[32];

    const int bt   = blockIdx.x;
    const int tid  = threadIdx.x;
    const int lane = tid & 63;
    const int wv   = tid >> 6;
    const int cg   = tid & 15;
    const int rg   = tid >> 4;

    const float* xbt = x + (size_t)bt * RR * FF;

    for (int i = tid; i < 128 * 32; i += 256) w2s[i] = w2[i];
    for (int i = tid; i < 128 * 64; i += 256)
        Whalf[i] = w1[(i >> 6) * 128 + 64 + (i & 63)];
    __syncthreads();

    float ups[4] = {0.f, 0.f, 0.f, 0.f};
    for (int tile = 0; tile < 12; ++tile) {
        const int rows0 = tile * 32;
        for (int rl = wv; rl < 32; rl += 4) {
            const int r = rows0 + rl;
            float2 v = make_float2(0.f, 0.f);
            if (r < RR) v = *(const float2*)&xbt[r * FF + 2 * lane];
            const float m = wsum64(v.x + v.y) * (1.f / 128.f);
            const float dx = v.x - m, dy = v.y - m;
            const float var = wsum64(dx * dx + dy * dy) * (1.f / 128.f);
            const float rstd = 1.f / sqrtf(var + 1e-5f);
            const float2 lw = *(const float2*)&ln_w[2 * lane];
            const float2 lb = *(const float2*)&ln_b[2 * lane];
            float2 o2;
            o2.x = dx * rstd * lw.x + lb.x;
            o2.y = dy * rstd * lw.y + lb.y;
            *(float2*)&xn[rl * 132 + 2 * lane] = o2;
        }
        __syncthreads();

        float4 a0 = {0, 0, 0, 0}, a1 = {0, 0, 0, 0};
        const int r0l = 2 * rg;
        const float* xr0 = &xn[r0l * 132];
        const float* xr1 = xr0 + 132;
        #pragma unroll 4
        for (int k = 0; k < 128; k += 4) {
            const float4 v0 = *(const float4*)(xr0 + k);
            const float4 v1 = *(const float4*)(xr1 + k);
            #pragma unroll
            for (int kk = 0; kk < 4; ++kk) {
                const float s0k = kk == 0 ? v0.x : (kk == 1 ? v0.y : (kk == 2 ? v0.z : v0.w));
                const float s1k = kk == 0 ? v1.x : (kk == 1 ? v1.y : (kk == 2 ? v1.z : v1.w));
                const float4 wvv = *(const float4*)&Whalf[(k + kk) * 64 + 4 * cg];
                fma4(a0, s0k, wvv);
                fma4(a1, s1k, wvv);
            }
        }
        if (rows0 + r0l < RR) {
            ups[0] += gelu_f(a0.x + b1[64 + 4 * cg + 0]);
            ups[1] += gelu_f(a0.y + b1[64 + 4 * cg + 1]);
            ups[2] += gelu_f(a0.z + b1[64 + 4 * cg + 2]);
            ups[3] += gelu_f(a0.w + b1[64 + 4 * cg + 3]);
        }
        if (rows0 + r0l + 1 < RR) {
            ups[0] += gelu_f(a1.x + b1[64 + 4 * cg + 0]);
            ups[1] += gelu_f(a1.y + b1[64 + 4 * cg + 1]);
            ups[2] += gelu_f(a1.z + b1[64 + 4 * cg + 2]);
            ups[3] += gelu_f(a1.w + b1[64 + 4 * cg + 3]);
        }
        __syncthreads();
    }

    #pragma unroll
    for (int c = 0; c < 4; ++c) part[rg * 64 + 4 * cg + c] = ups[c];
    __syncthreads();
    if (tid < 64) {
        float s = 0.f;
        for (int g = 0; g < 16; ++g) s += part[g * 64 + tid];
        globv[tid] = s / 374.f;
    }
    __syncthreads();
    if (tid < 32) {
        float a = b2[tid];
        for (int c = 0; c < 64; ++c)
            a = fmaf(globv[c], w2s[(64 + c) * 32 + tid], a);
        gvec[tid] = a;
    }
    __syncthreads();

    for (int i = tid; i < 128 * 64; i += 256)
        Whalf[i] = w1[(i >> 6) * 128 + (i & 63)];
    __syncthreads();

    for (int tile = 0; tile < 12; ++tile) {
        const int rows0 = tile * 32;
        for (int rl = wv; rl < 32; rl += 4) {
            const int r = rows0 + rl;
            float2 v = make_float2(0.f, 0.f);
            if (r < RR) v = *(const float2*)&xbt[r * FF + 2 * lane];
            const float m = wsum64(v.x + v.y) * (1.f / 128.f);
            const float dx = v.x - m, dy = v.y - m;
            const float var = wsum64(dx * dx + dy * dy) * (1.f / 128.f);
            const float rstd = 1.f / sqrtf(var + 1e-5f);
            const float2 lw = *(const float2*)&ln_w[2 * lane];
            const float2 lb = *(const float2*)&ln_b[2 * lane];
            float2 o2;
            o2.x = dx * rstd * lw.x + lb.x;
            o2.y = dy * rstd * lw.y + lb.y;
            *(float2*)&xn[rl * 132 + 2 * lane] = o2;
        }
        __syncthreads();

        float4 a0 = {0, 0, 0, 0}, a1 = {0, 0, 0, 0};
        const int r0l = 2 * rg;
        const float* xr0 = &xn[r0l * 132];
        const float* xr1 = xr0 + 132;
        #pragma unroll 4
        for (int k = 0; k < 128; k += 4) {
            const float4 v0 = *(const float4*)(xr0 + k);
            const float4 v1 = *(const float4*)(xr1 + k);
            #pragma unroll
            for (int kk = 0; kk < 4; ++kk) {
                const float s0k = kk == 0 ? v0.x : (kk == 1 ? v0.y : (kk == 2 ? v0.z : v0.w));
                const float s1k = kk == 0 ? v1.x : (kk == 1 ? v1.y : (kk == 2 ? v1.z : v1.w));
                const float4 wvv = *(const float4*)&Whalf[(k + kk) * 64 + 4 * cg];
                fma4(a0, s0k, wvv);
                fma4(a1, s1k, wvv);
            }
        }
        ltile[(r0l + 0) * 68 + 4 * cg + 0] = gelu_f(a0.x + b1[4 * cg + 0]);
        ltile[(r0l + 0) * 68 + 4 * cg + 1] = gelu_f(a0.y + b1[4 * cg + 1]);
        ltile[(r0l + 0) * 68 + 4 * cg + 2] = gelu_f(a0.z + b1[4 * cg + 2]);
        ltile[(r0l + 0) * 68 + 4 * cg + 3] = gelu_f(a0.w + b1[4 * cg + 3]);
        ltile[(r0l + 1) * 68 + 4 * cg + 0] = gelu_f(a1.x + b1[4 * cg + 0]);
        ltile[(r0l + 1) * 68 + 4 * cg + 1] = gelu_f(a1.y + b1[4 * cg + 1]);
        ltile[(r0l + 1) * 68 + 4 * cg + 2] = gelu_f(a1.z + b1[4 * cg + 2]);
        ltile[(r0l + 1) * 68 + 4 * cg + 3] = gelu_f(a1.w + b1[4 * cg + 3]);
        __syncthreads();

        {
            const int row = tid >> 3;
            const int jg  = tid & 7;
            const int r   = rows0 + row;
            float4 h2 = *(const float4*)&gvec[4 * jg];
            const float* lrow = &ltile[row * 68];
            #pragma unroll 8
            for (int c = 0; c < 64; ++c) {
                const float lv = lrow[c];
                const float4 wvv = *(const float4*)&w2s[c * 32 + 4 * jg];
                fma4(h2, lv, wvv);
            }
            float pl0 = 0.f, pl1 = 0.f;
            #pragma unroll
            for (int jj = 0; jj < 4; ++jj) {
                const int j = 4 * jg + jj;
                const float hv = jj == 0 ? h2.x : (jj == 1 ? h2.y : (jj == 2 ? h2.z : h2.w));
                const float ge = gelu_f(hv);
                pl0 = fmaf(ge, w3[2 * j + 0], pl0);
                pl1 = fmaf(ge, w3[2 * j + 1], pl1);
            }
            pl0 += __shfl_xor(pl0, 1); pl0 += __shfl_xor(pl0, 2); pl0 += __shfl_xor(pl0, 4);
            pl1 += __shfl_xor(pl1, 1); pl1 += __shfl_xor(pl1, 2); pl1 += __shfl_xor(pl1, 4);
            if (jg == 0 && r < RR) {
                const float l0 = pl0 + b3[0];
                const float l1 = pl1 + b3[1];
                const float m3 = fmaxf(l0, l1);
                const float e0 = expf(l0 - m3);
                const float e1 = expf(l1 - m3);
                const float sc = e1 / (e0 + e1);
                const float uu = u[(size_t)bt * RR + r];
                const float gmb = -logf(-logf(uu));
                s0out[(size_t)bt * RR + r] = sc + gmb;
            }
        }
        __syncthreads();
    }
}

// ===========================================================================
// Subset operator (exp-domain) + top-K bitonic sort. DPP z-reduce, rcp.
// ===========================================================================
__global__ __launch_bounds__(64) void k_subset(
    const float* __restrict__ s0, float* __restrict__ out)
{
    __shared__ unsigned long long keys[512];

    const int bt   = blockIdx.x;
    const int lane = threadIdx.x;

    float S[6], kh[6];
    #pragma unroll
    for (int i = 0; i < 6; ++i) {
        const int j = i * 64 + lane;
        S[i]  = (j < RR) ? expf(s0[(size_t)bt * RR + j]) : 0.f;  // s <= ~14.9
        kh[i] = 0.f;
    }

    for (int it = 0; it < KSEL; ++it) {
        const float z = wsum64(((S[0] + S[1]) + (S[2] + S[3])) + (S[4] + S[5]));
        const float inv = __builtin_amdgcn_rcpf(z);
        #pragma unroll
        for (int i = 0; i < 6; ++i) {
            const float oh = S[i] * inv;                    // softmax(s)
            kh[i] += oh;
            S[i] *= fmaxf(1.f - oh, 1.17549435e-38f);       // s += log(max(1-oh,EPS))
        }
    }

    #pragma unroll
    for (int i = 0; i < 6; ++i) {
        const int j = i * 64 + lane;
        if (j < RR) out[(size_t)bt * RR + j] = kh[i];
    }

    #pragma unroll
    for (int t = 0; t < 8; ++t) {
        const int idx = t * 64 + lane;
        unsigned long long key = 0ull;
        if (t < 6 && idx < RR) {
            key = (((unsigned long long)__float_as_uint(kh[t])) << 32)
                | (unsigned long long)(0xFFFFFFFFu - (unsigned)idx);
        }
        keys[idx] = key;
    }
    __syncthreads();

    for (int k = 2; k <= 512; k <<= 1) {
        for (int jj = k >> 1; jj > 0; jj >>= 1) {
            #pragma unroll
            for (int t = 0; t < 8; ++t) {
                const int i = t * 64 + lane;
                const int ixj = i ^ jj;
                if (ixj > i) {
                    const unsigned long long a = keys[i];
                    const unsigned long long b = keys[ixj];
                    const bool sw = ((i & k) == 0) ? (a < b) : (a > b);
                    if (sw) { keys[i] = b; keys[ixj] = a; }
                }
            }
            __syncthreads();
        }
    }

    for (int k2 = lane; k2 < KSEL; k2 += 64) {
        const unsigned idx = 0xFFFFFFFFu - (unsigned)(keys[k2] & 0xFFFFFFFFull);
        out[PROBN + (size_t)bt * KSEL + k2] = (float)idx;
    }
}

// ===========================================================================
extern "C" void kernel_launch(void* const* d_in, const int* in_sizes, int n_in,
                              void* d_out, int out_size, void* d_ws, size_t ws_size,
                              hipStream_t stream)
{
    const float* x    = (const float*)d_in[0];
    const float* u    = (const float*)d_in[1];
    const float* ln_w = (const float*)d_in[2];
    const float* ln_b = (const float*)d_in[3];
    const float* w1   = (const float*)d_in[4];
    const float* b1   = (const float*)d_in[5];
    const float* w2   = (const float*)d_in[6];
    const float* b2   = (const float*)d_in[7];
    const float* w3   = (const float*)d_in[8];
    const float* b3   = (const float*)d_in[9];

    float* s0  = (float*)d_ws;
    float* out = (float*)d_out;

    const size_t n_local = (size_t)NBT * RR * 64;
    const size_t n_part  = (size_t)NBT * NT * 64;
    const size_t n_gvec  = (size_t)NBT * 32;
    const size_t need    = ((size_t)PROBN + n_local + n_part + n_gvec) * sizeof(float);

    if (ws_size >= need) {
        float* localo = s0 + PROBN;
        float* parto  = localo + n_local;
        float* gvecb  = parto + n_part;
        k_gemm1<<<NBT * NT, 256, 0, stream>>>(x, ln_w, ln_b, w1, b1, localo, parto);
        k_gvec <<<NBT,      64,  0, stream>>>(parto, w2, b2, gvecb);
        k_score<<<NBT * 12, 256, 0, stream>>>(localo, gvecb, w2, w3, b3, u, s0);
    } else {
        k_front<<<NBT, 256, 0, stream>>>(x, u, ln_w, ln_b, w1, b1, w2, b2, w3, b3, s0);
    }
    k_subset<<<NBT, 64, 0, stream>>>(s0, out);
}